// Round 3
// baseline (85110.504 us; speedup 1.0000x reference)
//
#include <hip/hip_runtime.h>
#include <hip/hip_cooperative_groups.h>
#include <cmath>

namespace cg = cooperative_groups;

// ---------- high-accuracy double transcendentals ----------
__device__ __forceinline__ double dexp_(double x) {
    x = fmin(fmax(x, -64.0), 64.0);
    double w = x * 1.4426950408889634;     // log2(e)
    double n = rint(w);
    double u = (w - n) * 0.6931471805599453;
    double p = 1.0 + u * (1.0 + u * (0.5 + u * (1.6666666666666666e-01 +
               u * (4.1666666666666664e-02 + u * (8.3333333333333332e-03 +
               u * (1.3888888888888889e-03 + u * (1.9841269841269841e-04 +
               u * (2.4801587301587302e-05 + u * (2.7557319223985893e-06 +
               u * (2.7557319223985888e-07 + u * 2.5052108385441720e-08))))))))));
    return ldexp(p, (int)n);
}
__device__ __forceinline__ double dtanh_(double x) {
    double ax = fabs(x);
    double e = dexp_(2.0 * ax);
    double t = 1.0 - 2.0 / (e + 1.0);
    return copysign(t, x);
}
__device__ __forceinline__ double dsig_(double x) {
    return 1.0 / (1.0 + dexp_(-x));
}

// Gate-interleaved transposed weights: W[k][j*4+g], fused interleaved biases bR[j*4+g].
__global__ __launch_bounds__(256) void prep_kernel(
    const float* __restrict__ eWih, const float* __restrict__ eWhh,
    const float* __restrict__ ebih, const float* __restrict__ ebhh,
    const float* __restrict__ dWih, const float* __restrict__ dWhh,
    const float* __restrict__ dbih, const float* __restrict__ dbhh,
    float* __restrict__ WencR, double* __restrict__ bencR,
    float* __restrict__ WdecR, double* __restrict__ bdecR)
{
    const int n_enc = 257 * 1024;
    const int n_dec = 513 * 1024;
    const int total = n_enc + n_dec + 2048;
    for (int idx = blockIdx.x * blockDim.x + threadIdx.x; idx < total;
         idx += gridDim.x * blockDim.x) {
        if (idx < n_enc) {
            int k = idx >> 10, c = idx & 1023;
            int j = c >> 2, g = c & 3, r = g * 256 + j;
            WencR[idx] = (k == 0) ? eWih[r] : eWhh[r * 256 + (k - 1)];
        } else if (idx < n_enc + n_dec) {
            int i2 = idx - n_enc;
            int k = i2 >> 10, c = i2 & 1023;
            int j = c >> 2, g = c & 3, r = g * 256 + j;
            WdecR[i2] = (k < 257) ? dWih[r * 257 + k] : dWhh[r * 256 + (k - 257)];
        } else {
            int c = idx - n_enc - n_dec;
            if (c < 1024) {
                int r = (c & 3) * 256 + (c >> 2);
                bencR[c] = (double)ebih[r] + (double)ebhh[r];
            } else {
                int c2 = c - 1024;
                int r = (c2 & 3) * 256 + (c2 >> 2);
                bdecR[c2] = (double)dbih[r] + (double)dbhh[r];
            }
        }
    }
}

// ================= per-step LSTM/att bodies (shared by both paths) ==========

__device__ __forceinline__ void enc_tile_body(
    const float* __restrict__ x, const float* __restrict__ W,
    const double* __restrict__ bR, const float* __restrict__ h_in, long hstr,
    float* __restrict__ h_out, float* __restrict__ c_st, int t,
    int b0, int jg, int tid, int row, float* Xs)
{
    #pragma unroll
    for (int i = 0; i < 4; ++i) {
        int idx = tid + i * 256;
        int r = idx >> 6;
        int c4 = (idx & 63) * 4;
        float4 v = *(const float4*)&h_in[(long)(b0 + r) * hstr + c4];
        *(float4*)&Xs[r * 260 + c4] = v;
    }
    if (tid < 16) Xs[tid * 260 + 256] = x[(b0 + tid) * 256 + t];
    __syncthreads();

    const float* wp = W + jg * 4;
    double A0 = 0, A1 = 0, A2 = 0, A3 = 0;
    const float* xr = &Xs[row * 260];
    for (int k0 = 0; k0 < 256; k0 += 8) {
        float4 w[8];
        #pragma unroll
        for (int i = 0; i < 8; ++i)
            w[i] = *(const float4*)&wp[(1 + k0 + i) * 1024];
        float4 xa = *(const float4*)&xr[k0];
        float4 xb = *(const float4*)&xr[k0 + 4];
        float xs[8] = {xa.x, xa.y, xa.z, xa.w, xb.x, xb.y, xb.z, xb.w};
        float s0 = 0.f, s1 = 0.f, s2 = 0.f, s3 = 0.f;
        #pragma unroll
        for (int i = 0; i < 8; ++i) {
            s0 = fmaf(w[i].x, xs[i], s0);
            s1 = fmaf(w[i].y, xs[i], s1);
            s2 = fmaf(w[i].z, xs[i], s2);
            s3 = fmaf(w[i].w, xs[i], s3);
        }
        A0 += (double)s0; A1 += (double)s1;
        A2 += (double)s2; A3 += (double)s3;
    }
    {   // k = 0 : x_t
        float4 w = *(const float4*)&wp[0];
        float xv = xr[256];
        A0 += (double)(w.x * xv); A1 += (double)(w.y * xv);
        A2 += (double)(w.z * xv); A3 += (double)(w.w * xv);
    }

    double bi = bR[jg * 4 + 0], bf = bR[jg * 4 + 1];
    double bg = bR[jg * 4 + 2], bo = bR[jg * 4 + 3];
    int b = b0 + row;
    double iv = dsig_(A0 + bi);
    double fv = dsig_(A1 + bf);
    double gv = dtanh_(A2 + bg);
    double ov = dsig_(A3 + bo);
    long ci = (long)b * 256 + jg;
    double c = fv * (double)c_st[ci] + iv * gv;
    c_st[ci] = (float)c;
    h_out[(long)b * 65536 + jg] = (float)(ov * dtanh_(c));
}

__device__ __forceinline__ void dec_tile_body(
    const float* __restrict__ x, const int* __restrict__ y,
    const float* __restrict__ W, const double* __restrict__ bR,
    const float* __restrict__ di, const float* __restrict__ h_in, long hstr,
    float* __restrict__ h_out, float* __restrict__ c_st, int t,
    int b0, int jg, int tid, int row, float* Xs)
{
    #pragma unroll
    for (int i = 0; i < 4; ++i) {
        int idx = tid + i * 256;
        int r = idx >> 6;
        int c4 = (idx & 63) * 4;
        float4 v = *(const float4*)&di[(long)(b0 + r) * 256 + c4];
        *(float4*)&Xs[r * 516 + c4] = v;
        float4 u = *(const float4*)&h_in[(long)(b0 + r) * hstr + c4];
        *(float4*)&Xs[r * 516 + 260 + c4] = u;
    }
    if (tid < 16) {
        int b = b0 + tid;
        float dv = 0.0f;
        if (t > 0) {
            int yi = y[b * 256 + (t - 1)];
            dv = x[b * 256 + yi];
        }
        Xs[tid * 516 + 256] = dv;
    }
    __syncthreads();

    const float* wp = W + jg * 4;
    double A0 = 0, A1 = 0, A2 = 0, A3 = 0;
    const float* xr = &Xs[row * 516];

    // region 1: di (weights k=0..255)
    for (int k0 = 0; k0 < 256; k0 += 8) {
        float4 w[8];
        #pragma unroll
        for (int i = 0; i < 8; ++i)
            w[i] = *(const float4*)&wp[(k0 + i) * 1024];
        float4 xa = *(const float4*)&xr[k0];
        float4 xb = *(const float4*)&xr[k0 + 4];
        float xs[8] = {xa.x, xa.y, xa.z, xa.w, xb.x, xb.y, xb.z, xb.w};
        float s0 = 0.f, s1 = 0.f, s2 = 0.f, s3 = 0.f;
        #pragma unroll
        for (int i = 0; i < 8; ++i) {
            s0 = fmaf(w[i].x, xs[i], s0);
            s1 = fmaf(w[i].y, xs[i], s1);
            s2 = fmaf(w[i].z, xs[i], s2);
            s3 = fmaf(w[i].w, xs[i], s3);
        }
        A0 += (double)s0; A1 += (double)s1;
        A2 += (double)s2; A3 += (double)s3;
    }
    {   // k = 256 : dec_in
        float4 w = *(const float4*)&wp[256 * 1024];
        float xv = xr[256];
        A0 += (double)(w.x * xv); A1 += (double)(w.y * xv);
        A2 += (double)(w.z * xv); A3 += (double)(w.w * xv);
    }
    // region 2: h (weights k=257..512, Xs offset 260)
    for (int k0 = 0; k0 < 256; k0 += 8) {
        float4 w[8];
        #pragma unroll
        for (int i = 0; i < 8; ++i)
            w[i] = *(const float4*)&wp[(257 + k0 + i) * 1024];
        float4 xa = *(const float4*)&xr[260 + k0];
        float4 xb = *(const float4*)&xr[260 + k0 + 4];
        float xs[8] = {xa.x, xa.y, xa.z, xa.w, xb.x, xb.y, xb.z, xb.w};
        float s0 = 0.f, s1 = 0.f, s2 = 0.f, s3 = 0.f;
        #pragma unroll
        for (int i = 0; i < 8; ++i) {
            s0 = fmaf(w[i].x, xs[i], s0);
            s1 = fmaf(w[i].y, xs[i], s1);
            s2 = fmaf(w[i].z, xs[i], s2);
            s3 = fmaf(w[i].w, xs[i], s3);
        }
        A0 += (double)s0; A1 += (double)s1;
        A2 += (double)s2; A3 += (double)s3;
    }

    double bi = bR[jg * 4 + 0], bf = bR[jg * 4 + 1];
    double bg = bR[jg * 4 + 2], bo = bR[jg * 4 + 3];
    int b = b0 + row;
    double iv = dsig_(A0 + bi);
    double fv = dsig_(A1 + bf);
    double gv = dtanh_(A2 + bg);
    double ov = dsig_(A3 + bo);
    long ci = (long)b * 256 + jg;
    double c = fv * (double)c_st[ci] + iv * gv;
    c_st[ci] = (float)c;
    h_out[ci] = (float)(ov * dtanh_(c));
}

struct AttShared {
    float s_h[256];
    double s_V[12];
    double s_W2h[12];
    double s_ld[256];
    float s_e[256];
    double s_red[4];
    int s_redi[4];
    double s_maxd, s_Zd;
    int s_am;
};

__device__ __forceinline__ void att_tile_body(
    const double* __restrict__ encW1d, const float* __restrict__ enc_out,
    const float* __restrict__ W2,
    const float* __restrict__ h_in, long hstr, const int* __restrict__ y,
    float* __restrict__ di, float* __restrict__ logp_buf,
    float* __restrict__ out_pred, int t, int b, int tid, AttShared& sh)
{
    const int wid = tid >> 6, lane = tid & 63;

    sh.s_h[tid] = h_in[(long)b * hstr + tid];
    __syncthreads();

    for (int u = wid; u < 10; u += 4) {
        double p = 0.0;
        #pragma unroll
        for (int i = 0; i < 4; ++i) {
            int k = lane + i * 64;
            p += (double)W2[u * 256 + k] * (double)sh.s_h[k];
        }
        #pragma unroll
        for (int off = 32; off >= 1; off >>= 1) p += __shfl_down(p, off, 64);
        if (lane == 0) sh.s_W2h[u] = p;
    }
    __syncthreads();

    const double* eW = encW1d + ((long)b * 256 + tid) * 10;
    double l = 0.0;
    #pragma unroll
    for (int u = 0; u < 10; ++u) l += sh.s_V[u] * dtanh_(eW[u] + sh.s_W2h[u]);
    sh.s_ld[tid] = l;

    {   // argmax (first-index tie-break)
        double v = l; int idx = tid;
        #pragma unroll
        for (int off = 32; off >= 1; off >>= 1) {
            double v2 = __shfl_down(v, off, 64);
            int i2 = __shfl_down(idx, off, 64);
            if (v2 > v || (v2 == v && i2 < idx)) { v = v2; idx = i2; }
        }
        if (lane == 0) { sh.s_red[wid] = v; sh.s_redi[wid] = idx; }
    }
    __syncthreads();
    if (tid == 0) {
        double v = sh.s_red[0]; int idx = sh.s_redi[0];
        #pragma unroll
        for (int w2 = 1; w2 < 4; ++w2) {
            if (sh.s_red[w2] > v || (sh.s_red[w2] == v && sh.s_redi[w2] < idx)) {
                v = sh.s_red[w2]; idx = sh.s_redi[w2];
            }
        }
        sh.s_maxd = v; sh.s_am = idx;
    }
    __syncthreads();

    double e = dexp_(l - sh.s_maxd);
    sh.s_e[tid] = (float)e;
    {
        double v = e;
        #pragma unroll
        for (int off = 32; off >= 1; off >>= 1) v += __shfl_down(v, off, 64);
        if (lane == 0) sh.s_red[wid] = v;
    }
    __syncthreads();
    if (tid == 0) {
        double Z = sh.s_red[0] + sh.s_red[1] + sh.s_red[2] + sh.s_red[3];
        sh.s_Zd = Z;
        out_pred[t * 512 + b] = (float)sh.s_am;
        int yv = y[b * 256 + t];
        logp_buf[t * 512 + b] = (float)(sh.s_ld[yv] - sh.s_maxd - log(Z));
    }
    __syncthreads();

    const float rcpZ = (float)(1.0 / sh.s_Zd);
    const float* ep = enc_out + (long)b * 65536 + tid;
    float acc0 = 0.f, acc1 = 0.f, acc2 = 0.f, acc3 = 0.f;
    for (int s2 = 0; s2 < 256; s2 += 4) {
        acc0 += sh.s_e[s2 + 0] * ep[(s2 + 0) * 256];
        acc1 += sh.s_e[s2 + 1] * ep[(s2 + 1) * 256];
        acc2 += sh.s_e[s2 + 2] * ep[(s2 + 2) * 256];
        acc3 += sh.s_e[s2 + 3] * ep[(s2 + 3) * 256];
    }
    di[b * 256 + tid] = ((acc0 + acc1) + (acc2 + acc3)) * rcpZ;
}

// ====================== baseline per-step kernels (fallback) ================

__global__ __launch_bounds__(256) void lstm_enc_kernel(
    const float* __restrict__ x, const float* __restrict__ W,
    const double* __restrict__ bR, const float* __restrict__ h_in, long hin_str,
    float* __restrict__ h_out, float* __restrict__ c_st, int t)
{
    __shared__ float Xs[16 * 260];
    const int tid = threadIdx.x;
    const int b0  = (blockIdx.x & 31) * 16;
    const int jg  = (blockIdx.x >> 5) * 16 + (tid >> 4);
    enc_tile_body(x, W, bR, h_in, hin_str, h_out, c_st, t,
                  b0, jg, tid, tid & 15, Xs);
}

__global__ __launch_bounds__(256) void att_kernel(
    const double* __restrict__ encW1d, const float* __restrict__ enc_out,
    const float* __restrict__ W2, const float* __restrict__ V,
    const float* __restrict__ h_in, long hin_str, const int* __restrict__ y,
    float* __restrict__ di, float* __restrict__ logp_buf,
    float* __restrict__ out_pred, int t)
{
    __shared__ AttShared sh;
    const int tid = threadIdx.x;
    if (tid < 10) sh.s_V[tid] = (double)V[tid];
    att_tile_body(encW1d, enc_out, W2, h_in, hin_str, y,
                  di, logp_buf, out_pred, t, blockIdx.x, tid, sh);
}

__global__ __launch_bounds__(256) void lstm_dec_kernel(
    const float* __restrict__ x, const int* __restrict__ y,
    const float* __restrict__ W, const double* __restrict__ bR,
    const float* __restrict__ di, const float* __restrict__ h_in, long hin_str,
    float* __restrict__ h_out, float* __restrict__ c_st, int t)
{
    __shared__ float Xs[16 * 516];
    const int tid = threadIdx.x;
    const int b0  = (blockIdx.x & 31) * 16;
    const int jg  = (blockIdx.x >> 5) * 16 + (tid >> 4);
    dec_tile_body(x, y, W, bR, di, h_in, hin_str, h_out, c_st, t,
                  b0, jg, tid, tid & 15, Xs);
}

// ====================== cooperative persistent kernels ======================

__global__ __launch_bounds__(256, 2) void enc_loop_kernel(
    const float* __restrict__ x, const float* __restrict__ W,
    const double* __restrict__ bR, const float* __restrict__ hzero,
    float* __restrict__ enc_out, float* __restrict__ c_st, int nb)
{
    cg::grid_group grid = cg::this_grid();
    __shared__ float Xs[16 * 260];
    const int tid = threadIdx.x;
    const int row = tid & 15;
    const int jt  = tid >> 4;

    for (int t = 0; t < 256; ++t) {
        const float* h_in = (t == 0) ? hzero : (enc_out + (long)(t - 1) * 256);
        const long hstr = (t == 0) ? 256 : 65536;
        for (int tile = blockIdx.x; tile < 512; tile += nb) {
            const int b0 = (tile & 31) * 16;
            const int jg = (tile >> 5) * 16 + jt;
            enc_tile_body(x, W, bR, h_in, hstr,
                          enc_out + (long)t * 256, c_st, t,
                          b0, jg, tid, row, Xs);
            __syncthreads();   // protect Xs before next tile
        }
        __threadfence();
        grid.sync();
    }
}

__global__ __launch_bounds__(256, 2) void dec_loop_kernel(
    const double* __restrict__ encW1d, const float* __restrict__ enc_out,
    const float* __restrict__ W2, const float* __restrict__ V,
    const float* __restrict__ x, const int* __restrict__ y,
    const float* __restrict__ W, const double* __restrict__ bR,
    float* __restrict__ di, float* __restrict__ logp_buf,
    float* __restrict__ out_pred, float* __restrict__ hd,
    float* __restrict__ c_st, int nb)
{
    cg::grid_group grid = cg::this_grid();
    __shared__ float Xs[16 * 516];
    __shared__ AttShared sh;

    const int tid = threadIdx.x;
    const int row = tid & 15;
    const int jt  = tid >> 4;

    if (tid < 10) sh.s_V[tid] = (double)V[tid];   // loop-invariant

    for (int t = 0; t < 256; ++t) {
        const float* h_in = (t == 0) ? (enc_out + 255 * 256)
                                     : (hd + (t & 1) * 131072);
        const long hstr = (t == 0) ? 65536 : 256;
        float* h_out = hd + ((t + 1) & 1) * 131072;

        for (int tile = blockIdx.x; tile < 512; tile += nb) {
            att_tile_body(encW1d, enc_out, W2, h_in, hstr, y,
                          di, logp_buf, out_pred, t, tile, tid, sh);
            __syncthreads();
        }
        __threadfence();
        grid.sync();   // di ready for all blocks

        for (int tile = blockIdx.x; tile < 512; tile += nb) {
            const int b0 = (tile & 31) * 16;
            const int jg = (tile >> 5) * 16 + jt;
            dec_tile_body(x, y, W, bR, di, h_in, hstr, h_out, c_st, t,
                          b0, jg, tid, row, Xs);
            __syncthreads();
        }
        __threadfence();
        grid.sync();   // h ready for next att phase
    }
}

// ============================================================================

// encW1d[m*10+u] = sum_h enc_out[m][h] * W1[u][h]  (fp64 accum, one-shot)
__global__ __launch_bounds__(256) void encW1_kernel(
    const float* __restrict__ enc_out, const float* __restrict__ W1,
    double* __restrict__ encW1d)
{
    __shared__ float sa[64][260];
    __shared__ float sw[10][257];
    const int tid = threadIdx.x;
    const int m0 = blockIdx.x * 64;
    #pragma unroll
    for (int i = 0; i < 16; ++i) {
        int idx = tid + i * 256;
        int row = idx >> 6;
        int c4 = (idx & 63) * 4;
        const float4 v = *(const float4*)&enc_out[(long)(m0 + row) * 256 + c4];
        *(float4*)&sa[row][c4] = v;
    }
    for (int i = tid; i < 2560; i += 256) sw[i >> 8][i & 255] = W1[i];
    __syncthreads();
    for (int o = tid; o < 640; o += 256) {
        int r = o / 10;
        int u = o - r * 10;
        double acc = 0.0;
        #pragma unroll 4
        for (int k = 0; k < 256; ++k)
            acc += (double)sa[r][k] * (double)sw[u][k];
        encW1d[(long)(m0 + r) * 10 + u] = acc;
    }
}

__global__ __launch_bounds__(256) void loss_kernel(
    const float* __restrict__ logp_buf, float* __restrict__ out)
{
    const int tid = threadIdx.x;
    double acc = 0.0;
    for (int i = tid; i < 131072; i += 256) acc += (double)logp_buf[i];
    __shared__ double s_red[4];
    const int wid = tid >> 6, lane = tid & 63;
    #pragma unroll
    for (int off = 32; off >= 1; off >>= 1) acc += __shfl_down(acc, off, 64);
    if (lane == 0) s_red[wid] = acc;
    __syncthreads();
    if (tid == 0) {
        out[131072] = (float)(-(s_red[0] + s_red[1] + s_red[2] + s_red[3])
                              / (512.0 * 512.0));
    }
}

extern "C" void kernel_launch(void* const* d_in, const int* in_sizes, int n_in,
                              void* d_out, int out_size, void* d_ws, size_t ws_size,
                              hipStream_t stream)
{
    const float* x    = (const float*)d_in[0];
    const int*   y    = (const int*)  d_in[1];
    const float* eWih = (const float*)d_in[2];
    const float* eWhh = (const float*)d_in[3];
    const float* ebih = (const float*)d_in[4];
    const float* ebhh = (const float*)d_in[5];
    const float* dWih = (const float*)d_in[6];
    const float* dWhh = (const float*)d_in[7];
    const float* dbih = (const float*)d_in[8];
    const float* dbhh = (const float*)d_in[9];
    const float* W1   = (const float*)d_in[10];
    const float* W2   = (const float*)d_in[11];
    const float* V    = (const float*)d_in[12];

    double* encW1d = (double*)d_ws;             // 1310720 doubles
    double* bencR  = encW1d + 1310720;          // 1024
    double* bdecR  = bencR + 1024;              // 1024
    float* enc_out = (float*)(bdecR + 1024);    // [512][256][256] (b,s,h)
    float* c_st    = enc_out + 33554432;        // 131072
    float* hzero   = c_st + 131072;             // 131072
    float* hd      = hzero + 131072;            // 2 x 131072
    float* dibuf   = hd + 262144;               // 131072
    float* logp    = dibuf + 131072;            // 131072
    float* WencR   = logp + 131072;             // 263168
    float* WdecR   = WencR + 263168;            // 525312

    float* out = (float*)d_out;

    // --- occupancy-sized cooperative grids (cached) ---
    static int s_nb_enc = -1, s_nb_dec = -1;
    if (s_nb_enc < 0) {
        int dev = 0;
        hipGetDevice(&dev);
        hipDeviceProp_t prop;
        int ncu = 0;
        if (hipGetDeviceProperties(&prop, dev) == hipSuccess)
            ncu = prop.multiProcessorCount;
        int occe = 0, occd = 0;
        hipOccupancyMaxActiveBlocksPerMultiprocessor(
            &occe, reinterpret_cast<const void*>(enc_loop_kernel), 256, 0);
        hipOccupancyMaxActiveBlocksPerMultiprocessor(
            &occd, reinterpret_cast<const void*>(dec_loop_kernel), 256, 0);
        long ne = (long)occe * ncu, nd = (long)occd * ncu;
        s_nb_enc = (int)(ne > 512 ? 512 : ne);
        s_nb_dec = (int)(nd > 512 ? 512 : nd);
    }
    int nb_enc = s_nb_enc, nb_dec = s_nb_dec;

    hipMemsetAsync(c_st, 0, 131072 * sizeof(float), stream);
    hipMemsetAsync(hzero, 0, 131072 * sizeof(float), stream);

    prep_kernel<<<512, 256, 0, stream>>>(eWih, eWhh, ebih, ebhh,
                                         dWih, dWhh, dbih, dbhh,
                                         WencR, bencR, WdecR, bdecR);

    // ---------------- encoder ----------------
    bool enc_done = false;
    if (nb_enc > 0) {
        void* args[] = { (void*)&x, (void*)&WencR, (void*)&bencR,
                         (void*)&hzero, (void*)&enc_out, (void*)&c_st,
                         (void*)&nb_enc };
        hipError_t e = hipLaunchCooperativeKernel(
            reinterpret_cast<const void*>(enc_loop_kernel),
            dim3(nb_enc), dim3(256), args, 0, stream);
        enc_done = (e == hipSuccess);
    }
    if (!enc_done) {
        for (int t = 0; t < 256; ++t) {
            const float* hin; long hstr;
            if (t == 0) { hin = hzero; hstr = 256; }
            else        { hin = enc_out + (long)(t - 1) * 256; hstr = 65536; }
            lstm_enc_kernel<<<512, 256, 0, stream>>>(x, WencR, bencR, hin, hstr,
                                                     enc_out + (long)t * 256,
                                                     c_st, t);
        }
    }

    encW1_kernel<<<2048, 256, 0, stream>>>(enc_out, W1, encW1d);

    // ---------------- decoder ----------------
    bool dec_done = false;
    if (nb_dec > 0) {
        void* args[] = { (void*)&encW1d, (void*)&enc_out, (void*)&W2, (void*)&V,
                         (void*)&x, (void*)&y, (void*)&WdecR, (void*)&bdecR,
                         (void*)&dibuf, (void*)&logp, (void*)&out, (void*)&hd,
                         (void*)&c_st, (void*)&nb_dec };
        hipError_t e = hipLaunchCooperativeKernel(
            reinterpret_cast<const void*>(dec_loop_kernel),
            dim3(nb_dec), dim3(256), args, 0, stream);
        dec_done = (e == hipSuccess);
    }
    if (!dec_done) {
        for (int t = 0; t < 256; ++t) {
            const float* hin; long hstr;
            if (t == 0) { hin = enc_out + 255 * 256; hstr = 65536; }
            else        { hin = hd + (t & 1) * 131072; hstr = 256; }
            float* hout = hd + ((t + 1) & 1) * 131072;
            att_kernel<<<512, 256, 0, stream>>>(encW1d, enc_out, W2, V, hin,
                                                hstr, y, dibuf, logp, out, t);
            lstm_dec_kernel<<<512, 256, 0, stream>>>(x, y, WdecR, bdecR, dibuf,
                                                     hin, hstr, hout, c_st, t);
        }
    }

    loss_kernel<<<1, 256, 0, stream>>>(logp, out);
}

// Round 4
// 23999.408 us; speedup vs baseline: 3.5464x; 3.5464x over previous
//
#include <hip/hip_runtime.h>
#include <cmath>

// ---------- high-accuracy double transcendentals ----------
__device__ __forceinline__ double dexp_(double x) {
    x = fmin(fmax(x, -64.0), 64.0);
    double w = x * 1.4426950408889634;     // log2(e)
    double n = rint(w);
    double u = (w - n) * 0.6931471805599453;
    double p = 1.0 + u * (1.0 + u * (0.5 + u * (1.6666666666666666e-01 +
               u * (4.1666666666666664e-02 + u * (8.3333333333333332e-03 +
               u * (1.3888888888888889e-03 + u * (1.9841269841269841e-04 +
               u * (2.4801587301587302e-05 + u * (2.7557319223985893e-06 +
               u * (2.7557319223985888e-07 + u * 2.5052108385441720e-08))))))))));
    return ldexp(p, (int)n);
}
__device__ __forceinline__ double dtanh_(double x) {
    double ax = fabs(x);
    double e = dexp_(2.0 * ax);
    double t = 1.0 - 2.0 / (e + 1.0);
    return copysign(t, x);
}
__device__ __forceinline__ double dsig_(double x) {
    return 1.0 / (1.0 + dexp_(-x));
}

// Gate-interleaved transposed weights: W[k][j*4+g], fused interleaved biases bR[j*4+g].
__global__ __launch_bounds__(256) void prep_kernel(
    const float* __restrict__ eWih, const float* __restrict__ eWhh,
    const float* __restrict__ ebih, const float* __restrict__ ebhh,
    const float* __restrict__ dWih, const float* __restrict__ dWhh,
    const float* __restrict__ dbih, const float* __restrict__ dbhh,
    float* __restrict__ WencR, double* __restrict__ bencR,
    float* __restrict__ WdecR, double* __restrict__ bdecR)
{
    const int n_enc = 257 * 1024;
    const int n_dec = 513 * 1024;
    const int total = n_enc + n_dec + 2048;
    for (int idx = blockIdx.x * blockDim.x + threadIdx.x; idx < total;
         idx += gridDim.x * blockDim.x) {
        if (idx < n_enc) {
            int k = idx >> 10, c = idx & 1023;
            int j = c >> 2, g = c & 3, r = g * 256 + j;
            WencR[idx] = (k == 0) ? eWih[r] : eWhh[r * 256 + (k - 1)];
        } else if (idx < n_enc + n_dec) {
            int i2 = idx - n_enc;
            int k = i2 >> 10, c = i2 & 1023;
            int j = c >> 2, g = c & 3, r = g * 256 + j;
            WdecR[i2] = (k < 257) ? dWih[r * 257 + k] : dWhh[r * 256 + (k - 257)];
        } else {
            int c = idx - n_enc - n_dec;
            if (c < 1024) {
                int r = (c & 3) * 256 + (c >> 2);
                bencR[c] = (double)ebih[r] + (double)ebhh[r];
            } else {
                int c2 = c - 1024;
                int r = (c2 & 3) * 256 + (c2 >> 2);
                bdecR[c2] = (double)dbih[r] + (double)dbhh[r];
            }
        }
    }
}

// ===================== fused persistent encoder =====================
// 128 blocks x 4 batches/block. Thread tid owns hidden unit tid (4 gates)
// for all 4 batches. h lives in LDS (double-buffered), c in registers.
// Per-output arithmetic is bit-identical to the verified per-step kernel:
// same 8-k fp32 FMA blocks -> fp64 accumulate, x-term last, same gate fns,
// same float rounding of c and h each step.
__global__ __launch_bounds__(256) void enc_fused_kernel(
    const float* __restrict__ x, const float* __restrict__ W,
    const double* __restrict__ bR, float* __restrict__ enc_out,
    float* __restrict__ c_st)
{
    __shared__ float h_lds[2][4][256];
    __shared__ float xs[2][4];
    const int tid = threadIdx.x;
    const int b0g = blockIdx.x * 4;

    #pragma unroll
    for (int bb = 0; bb < 4; ++bb) h_lds[0][bb][tid] = 0.0f;

    float c_f[4] = {0.f, 0.f, 0.f, 0.f};
    const double bi = bR[tid * 4 + 0], bf = bR[tid * 4 + 1];
    const double bg = bR[tid * 4 + 2], bo = bR[tid * 4 + 3];
    const float* wcol = W + tid * 4;

    for (int t = 0; t < 256; ++t) {
        const int cur = t & 1, nxt = cur ^ 1;
        if (tid < 4) xs[cur][tid] = x[(b0g + tid) * 256 + t];
        __syncthreads();   // publish h_lds[cur] (prev iter) and xs[cur]

        double A[4][4];
        #pragma unroll
        for (int bb = 0; bb < 4; ++bb) {
            #pragma unroll
            for (int g = 0; g < 4; ++g) A[bb][g] = 0.0;
        }

        for (int k0 = 0; k0 < 256; k0 += 8) {
            float4 w[8];
            #pragma unroll
            for (int i = 0; i < 8; ++i)
                w[i] = *(const float4*)&wcol[(1 + k0 + i) * 1024];
            #pragma unroll
            for (int bb = 0; bb < 4; ++bb) {
                float4 xa = *(const float4*)&h_lds[cur][bb][k0];
                float4 xb = *(const float4*)&h_lds[cur][bb][k0 + 4];
                float xv[8] = {xa.x, xa.y, xa.z, xa.w, xb.x, xb.y, xb.z, xb.w};
                float s0 = 0.f, s1 = 0.f, s2 = 0.f, s3 = 0.f;
                #pragma unroll
                for (int i = 0; i < 8; ++i) {
                    s0 = fmaf(w[i].x, xv[i], s0);
                    s1 = fmaf(w[i].y, xv[i], s1);
                    s2 = fmaf(w[i].z, xv[i], s2);
                    s3 = fmaf(w[i].w, xv[i], s3);
                }
                A[bb][0] += (double)s0; A[bb][1] += (double)s1;
                A[bb][2] += (double)s2; A[bb][3] += (double)s3;
            }
        }
        {   // k = 0 : x_t
            float4 w = *(const float4*)&wcol[0];
            #pragma unroll
            for (int bb = 0; bb < 4; ++bb) {
                float xv = xs[cur][bb];
                A[bb][0] += (double)(w.x * xv); A[bb][1] += (double)(w.y * xv);
                A[bb][2] += (double)(w.z * xv); A[bb][3] += (double)(w.w * xv);
            }
        }

        #pragma unroll
        for (int bb = 0; bb < 4; ++bb) {
            double iv = dsig_(A[bb][0] + bi);
            double fv = dsig_(A[bb][1] + bf);
            double gv = dtanh_(A[bb][2] + bg);
            double ov = dsig_(A[bb][3] + bo);
            double c = fv * (double)c_f[bb] + iv * gv;
            c_f[bb] = (float)c;
            float hv = (float)(ov * dtanh_(c));
            enc_out[(long)(b0g + bb) * 65536 + t * 256 + tid] = hv;
            h_lds[nxt][bb][tid] = hv;
        }
        __syncthreads();   // h_lds[nxt] complete before next iteration
    }

    #pragma unroll
    for (int bb = 0; bb < 4; ++bb)
        c_st[(long)(b0g + bb) * 256 + tid] = c_f[bb];   // handoff to decoder
}

// encW1d[m*10+u] = sum_h enc_out[m][h] * W1[u][h]  (fp64 accum, one-shot)
__global__ __launch_bounds__(256) void encW1_kernel(
    const float* __restrict__ enc_out, const float* __restrict__ W1,
    double* __restrict__ encW1d)
{
    __shared__ float sa[64][260];
    __shared__ float sw[10][257];
    const int tid = threadIdx.x;
    const int m0 = blockIdx.x * 64;
    #pragma unroll
    for (int i = 0; i < 16; ++i) {
        int idx = tid + i * 256;
        int row = idx >> 6;
        int c4 = (idx & 63) * 4;
        const float4 v = *(const float4*)&enc_out[(long)(m0 + row) * 256 + c4];
        *(float4*)&sa[row][c4] = v;
    }
    for (int i = tid; i < 2560; i += 256) sw[i >> 8][i & 255] = W1[i];
    __syncthreads();
    for (int o = tid; o < 640; o += 256) {
        int r = o / 10;
        int u = o - r * 10;
        double acc = 0.0;
        #pragma unroll 4
        for (int k = 0; k < 256; ++k)
            acc += (double)sa[r][k] * (double)sw[u][k];
        encW1d[(long)(m0 + r) * 10 + u] = acc;
    }
}

// ===================== fused persistent decoder =====================
// 128 blocks x 4 batches/block; all 256 timesteps in-kernel.
// Per step: phase A = per-batch attention softmax (256 threads serve one
// batch at a time; identical shuffle/reduction order to verified kernel),
// phase B = di accumulation interleaved across the 4 batches (per-batch
// fp32 summation order unchanged), then the dec LSTM (thread tid = unit tid,
// 4 gates, 4 batches; identical 8-k block structure and fp64 accumulate).
// h and di live in LDS; c in registers. No grid-wide sync anywhere.
__global__ __launch_bounds__(256) void dec_fused_kernel(
    const double* __restrict__ encW1d, const float* __restrict__ enc_out,
    const float* __restrict__ W2, const float* __restrict__ V,
    const float* __restrict__ x, const int* __restrict__ y,
    const float* __restrict__ W, const double* __restrict__ bR,
    const float* __restrict__ c_init, float* __restrict__ logp_buf,
    float* __restrict__ out_pred)
{
    __shared__ float h_lds[2][4][256];
    __shared__ float di_lds[4][256];
    __shared__ float e_lds[4][256];
    __shared__ float rcpZ_lds[4];
    __shared__ float din_lds[4];
    __shared__ double s_V[12];
    __shared__ double s_W2h[12];
    __shared__ double s_ld[256];
    __shared__ double s_red[4];
    __shared__ int s_redi[4];
    __shared__ double s_maxd;
    __shared__ int s_am;

    const int tid = threadIdx.x;
    const int wid = tid >> 6, lane = tid & 63;
    const int b0g = blockIdx.x * 4;

    if (tid < 10) s_V[tid] = (double)V[tid];
    #pragma unroll
    for (int bb = 0; bb < 4; ++bb)
        h_lds[0][bb][tid] = enc_out[(long)(b0g + bb) * 65536 + 255 * 256 + tid];
    float c_f[4];
    #pragma unroll
    for (int bb = 0; bb < 4; ++bb)
        c_f[bb] = c_init[(long)(b0g + bb) * 256 + tid];
    const double bi = bR[tid * 4 + 0], bf = bR[tid * 4 + 1];
    const double bg = bR[tid * 4 + 2], bo = bR[tid * 4 + 3];
    const float* wcol = W + tid * 4;
    __syncthreads();

    for (int t = 0; t < 256; ++t) {
        const int cur = t & 1, nxt = cur ^ 1;

        // ---------------- phase A: per-batch attention softmax ----------
        for (int bb = 0; bb < 4; ++bb) {
            const int b = b0g + bb;
            const float* hh = h_lds[cur][bb];

            for (int u = wid; u < 10; u += 4) {
                double p = 0.0;
                #pragma unroll
                for (int i = 0; i < 4; ++i) {
                    int k = lane + i * 64;
                    p += (double)W2[u * 256 + k] * (double)hh[k];
                }
                #pragma unroll
                for (int off = 32; off >= 1; off >>= 1) p += __shfl_down(p, off, 64);
                if (lane == 0) s_W2h[u] = p;
            }
            __syncthreads();

            const double* eW = encW1d + ((long)b * 256 + tid) * 10;
            double l = 0.0;
            #pragma unroll
            for (int u = 0; u < 10; ++u) l += s_V[u] * dtanh_(eW[u] + s_W2h[u]);
            s_ld[tid] = l;

            {   // argmax (first-index tie-break)
                double v = l; int idx = tid;
                #pragma unroll
                for (int off = 32; off >= 1; off >>= 1) {
                    double v2 = __shfl_down(v, off, 64);
                    int i2 = __shfl_down(idx, off, 64);
                    if (v2 > v || (v2 == v && i2 < idx)) { v = v2; idx = i2; }
                }
                if (lane == 0) { s_red[wid] = v; s_redi[wid] = idx; }
            }
            __syncthreads();
            if (tid == 0) {
                double v = s_red[0]; int idx = s_redi[0];
                #pragma unroll
                for (int w2 = 1; w2 < 4; ++w2) {
                    if (s_red[w2] > v || (s_red[w2] == v && s_redi[w2] < idx)) {
                        v = s_red[w2]; idx = s_redi[w2];
                    }
                }
                s_maxd = v; s_am = idx;
            }
            __syncthreads();

            double e = dexp_(l - s_maxd);
            e_lds[bb][tid] = (float)e;
            {
                double v = e;
                #pragma unroll
                for (int off = 32; off >= 1; off >>= 1) v += __shfl_down(v, off, 64);
                if (lane == 0) s_red[wid] = v;
            }
            __syncthreads();
            if (tid == 0) {
                double Z = s_red[0] + s_red[1] + s_red[2] + s_red[3];
                rcpZ_lds[bb] = (float)(1.0 / Z);
                out_pred[t * 512 + b] = (float)s_am;
                int yv = y[b * 256 + t];
                logp_buf[t * 512 + b] = (float)(s_ld[yv] - s_maxd - log(Z));
            }
            __syncthreads();   // protect s_* reuse for next bb / phase B
        }

        // ---------------- phase B: di (interleaved across batches) -------
        {
            float acc[4][4];
            #pragma unroll
            for (int bb = 0; bb < 4; ++bb) {
                #pragma unroll
                for (int g = 0; g < 4; ++g) acc[bb][g] = 0.f;
            }
            for (int s2 = 0; s2 < 256; s2 += 4) {
                #pragma unroll
                for (int bb = 0; bb < 4; ++bb) {
                    const float* ep = enc_out + (long)(b0g + bb) * 65536 + tid;
                    acc[bb][0] += e_lds[bb][s2 + 0] * ep[(s2 + 0) * 256];
                    acc[bb][1] += e_lds[bb][s2 + 1] * ep[(s2 + 1) * 256];
                    acc[bb][2] += e_lds[bb][s2 + 2] * ep[(s2 + 2) * 256];
                    acc[bb][3] += e_lds[bb][s2 + 3] * ep[(s2 + 3) * 256];
                }
            }
            #pragma unroll
            for (int bb = 0; bb < 4; ++bb)
                di_lds[bb][tid] = ((acc[bb][0] + acc[bb][1]) +
                                   (acc[bb][2] + acc[bb][3])) * rcpZ_lds[bb];
        }
        if (tid < 4) {   // dec_in (teacher forcing)
            int b = b0g + tid;
            float dv = 0.0f;
            if (t > 0) { int yi = y[b * 256 + (t - 1)]; dv = x[b * 256 + yi]; }
            din_lds[tid] = dv;
        }
        __syncthreads();   // di_lds, din_lds ready

        // ---------------- dec LSTM ----------------
        double A[4][4];
        #pragma unroll
        for (int bb = 0; bb < 4; ++bb) {
            #pragma unroll
            for (int g = 0; g < 4; ++g) A[bb][g] = 0.0;
        }

        // region 1: di (weight rows 0..255)
        for (int k0 = 0; k0 < 256; k0 += 8) {
            float4 w[8];
            #pragma unroll
            for (int i = 0; i < 8; ++i)
                w[i] = *(const float4*)&wcol[(k0 + i) * 1024];
            #pragma unroll
            for (int bb = 0; bb < 4; ++bb) {
                float4 xa = *(const float4*)&di_lds[bb][k0];
                float4 xb = *(const float4*)&di_lds[bb][k0 + 4];
                float xv[8] = {xa.x, xa.y, xa.z, xa.w, xb.x, xb.y, xb.z, xb.w};
                float s0 = 0.f, s1 = 0.f, s2 = 0.f, s3 = 0.f;
                #pragma unroll
                for (int i = 0; i < 8; ++i) {
                    s0 = fmaf(w[i].x, xv[i], s0);
                    s1 = fmaf(w[i].y, xv[i], s1);
                    s2 = fmaf(w[i].z, xv[i], s2);
                    s3 = fmaf(w[i].w, xv[i], s3);
                }
                A[bb][0] += (double)s0; A[bb][1] += (double)s1;
                A[bb][2] += (double)s2; A[bb][3] += (double)s3;
            }
        }
        {   // k = 256 : dec_in
            float4 w = *(const float4*)&wcol[256 * 1024];
            #pragma unroll
            for (int bb = 0; bb < 4; ++bb) {
                float xv = din_lds[bb];
                A[bb][0] += (double)(w.x * xv); A[bb][1] += (double)(w.y * xv);
                A[bb][2] += (double)(w.z * xv); A[bb][3] += (double)(w.w * xv);
            }
        }
        // region 2: h (weight rows 257..512)
        for (int k0 = 0; k0 < 256; k0 += 8) {
            float4 w[8];
            #pragma unroll
            for (int i = 0; i < 8; ++i)
                w[i] = *(const float4*)&wcol[(257 + k0 + i) * 1024];
            #pragma unroll
            for (int bb = 0; bb < 4; ++bb) {
                float4 xa = *(const float4*)&h_lds[cur][bb][k0];
                float4 xb = *(const float4*)&h_lds[cur][bb][k0 + 4];
                float xv[8] = {xa.x, xa.y, xa.z, xa.w, xb.x, xb.y, xb.z, xb.w};
                float s0 = 0.f, s1 = 0.f, s2 = 0.f, s3 = 0.f;
                #pragma unroll
                for (int i = 0; i < 8; ++i) {
                    s0 = fmaf(w[i].x, xv[i], s0);
                    s1 = fmaf(w[i].y, xv[i], s1);
                    s2 = fmaf(w[i].z, xv[i], s2);
                    s3 = fmaf(w[i].w, xv[i], s3);
                }
                A[bb][0] += (double)s0; A[bb][1] += (double)s1;
                A[bb][2] += (double)s2; A[bb][3] += (double)s3;
            }
        }

        #pragma unroll
        for (int bb = 0; bb < 4; ++bb) {
            double iv = dsig_(A[bb][0] + bi);
            double fv = dsig_(A[bb][1] + bf);
            double gv = dtanh_(A[bb][2] + bg);
            double ov = dsig_(A[bb][3] + bo);
            double c = fv * (double)c_f[bb] + iv * gv;
            c_f[bb] = (float)c;
            h_lds[nxt][bb][tid] = (float)(ov * dtanh_(c));
        }
        __syncthreads();   // publish h_lds[nxt]
    }
}

__global__ __launch_bounds__(256) void loss_kernel(
    const float* __restrict__ logp_buf, float* __restrict__ out)
{
    const int tid = threadIdx.x;
    double acc = 0.0;
    for (int i = tid; i < 131072; i += 256) acc += (double)logp_buf[i];
    __shared__ double s_red[4];
    const int wid = tid >> 6, lane = tid & 63;
    #pragma unroll
    for (int off = 32; off >= 1; off >>= 1) acc += __shfl_down(acc, off, 64);
    if (lane == 0) s_red[wid] = acc;
    __syncthreads();
    if (tid == 0) {
        out[131072] = (float)(-(s_red[0] + s_red[1] + s_red[2] + s_red[3])
                              / (512.0 * 512.0));
    }
}

extern "C" void kernel_launch(void* const* d_in, const int* in_sizes, int n_in,
                              void* d_out, int out_size, void* d_ws, size_t ws_size,
                              hipStream_t stream)
{
    const float* x    = (const float*)d_in[0];
    const int*   y    = (const int*)  d_in[1];
    const float* eWih = (const float*)d_in[2];
    const float* eWhh = (const float*)d_in[3];
    const float* ebih = (const float*)d_in[4];
    const float* ebhh = (const float*)d_in[5];
    const float* dWih = (const float*)d_in[6];
    const float* dWhh = (const float*)d_in[7];
    const float* dbih = (const float*)d_in[8];
    const float* dbhh = (const float*)d_in[9];
    const float* W1   = (const float*)d_in[10];
    const float* W2   = (const float*)d_in[11];
    const float* V    = (const float*)d_in[12];

    double* encW1d = (double*)d_ws;             // 1310720 doubles
    double* bencR  = encW1d + 1310720;          // 1024
    double* bdecR  = bencR + 1024;              // 1024
    float* enc_out = (float*)(bdecR + 1024);    // [512][256][256] (b,s,h)
    float* c_st    = enc_out + 33554432;        // 131072
    float* hzero   = c_st + 131072;             // 131072 (unused)
    float* hd      = hzero + 131072;            // 2 x 131072 (unused)
    float* dibuf   = hd + 262144;               // 131072 (unused)
    float* logp    = dibuf + 131072;            // 131072
    float* WencR   = logp + 131072;             // 263168
    float* WdecR   = WencR + 263168;            // 525312

    float* out = (float*)d_out;

    prep_kernel<<<512, 256, 0, stream>>>(eWih, eWhh, ebih, ebhh,
                                         dWih, dWhh, dbih, dbhh,
                                         WencR, bencR, WdecR, bdecR);

    enc_fused_kernel<<<128, 256, 0, stream>>>(x, WencR, bencR, enc_out, c_st);

    encW1_kernel<<<2048, 256, 0, stream>>>(enc_out, W1, encW1d);

    dec_fused_kernel<<<128, 256, 0, stream>>>(encW1d, enc_out, W2, V, x, y,
                                              WdecR, bdecR, c_st, logp, out);

    loss_kernel<<<1, 256, 0, stream>>>(logp, out);
}